// Round 1
// baseline (723.391 us; speedup 1.0000x reference)
//
#include <hip/hip_runtime.h>

// Problem constants (fixed by reference): B=32, C=256, H=W=128, K=3, reflect pad 1.
constexpr int Bc = 32;
constexpr int Cc = 256;
constexpr int Hc = 128;
constexpr int Wc = 128;
constexpr int HWc = Hc * Wc;
constexpr int CHUNKS = 4;           // channel split for occupancy (64 ch per block)
constexpr int CPC = Cc / CHUNKS;    // 64
constexpr int ROWS = 16;            // output rows per block tile
constexpr int TILES = Hc / ROWS;    // 8

// d_out is poisoned 0xAA before every timed launch; conv kernel atomically
// accumulates per-chunk partials, so zero first (stream-ordered).
__global__ __launch_bounds__(512) void zero_out_kernel(float4* __restrict__ out4) {
    int i = blockIdx.x * 512 + threadIdx.x;   // 512 blocks x 512 thr = 262144 float4 = 1,048,576 floats
    out4[i] = make_float4(0.f, 0.f, 0.f, 0.f);
}

__global__ __launch_bounds__(512) void modbank_kernel(
    const float* __restrict__ x,        // [B,C,H,W]
    const float* __restrict__ ku,       // [9,1,C,3,3]
    const float* __restrict__ kv,       // [9,1,C,3,3]
    const int*   __restrict__ ui,       // [B]
    const int*   __restrict__ vi,       // [B]
    float* __restrict__ out)            // [B,2,H,W]
{
    // Weights for this block's 64 channels, padded to stride 12 floats (3 float4)
    // so reads are aligned ds_read_b128 broadcasts.
    __shared__ float4 swu[CPC * 3];
    __shared__ float4 swv[CPC * 3];

    const int tile  = blockIdx.x;        // 0..7   row tile
    const int b     = blockIdx.y;        // 0..31  batch
    const int chunk = blockIdx.z;        // 0..3   channel chunk
    const int c0    = chunk * CPC;
    const int tid   = threadIdx.x;       // 0..511

    // ---- stage weights into LDS (uniform per block) ----
    const int uview = ui[b];
    const int vview = vi[b];
    const float* gu = ku + (size_t)uview * (Cc * 9) + c0 * 9;
    const float* gv = kv + (size_t)vview * (Cc * 9) + c0 * 9;
    float* su = (float*)swu;
    float* sv = (float*)swv;
    for (int i = tid; i < CPC * 9; i += 512) {
        int c = i / 9;
        int k = i - c * 9;
        su[c * 12 + k] = gu[i];
        sv[c * 12 + k] = gv[i];
    }
    __syncthreads();

    // ---- thread -> (row, 4-wide col group) ----
    const int w4 = tid & 31;             // float4 index along W (32*4 = 128)
    const int r  = tid >> 5;             // 0..15 row within tile
    const int h  = tile * ROWS + r;
    const int hm = (h == 0)      ? 1      : h - 1;   // reflect
    const int hp = (h == Hc - 1) ? Hc - 2 : h + 1;   // reflect

    const float* pm = x + ((size_t)(b * Cc + c0) * Hc + hm) * Wc + w4 * 4;
    const float* p0 = x + ((size_t)(b * Cc + c0) * Hc + h ) * Wc + w4 * 4;
    const float* pp = x + ((size_t)(b * Cc + c0) * Hc + hp) * Wc + w4 * 4;

    float4 au = make_float4(0.f, 0.f, 0.f, 0.f);
    float4 av = make_float4(0.f, 0.f, 0.f, 0.f);

    // 3-tap horizontal accumulate for one input row into one float4 accumulator.
    auto row_acc = [](float l, const float4& v, float rt,
                      float wa, float wb, float wc, float4& acc) {
        acc.x = fmaf(l,   wa, fmaf(v.x, wb, fmaf(v.y, wc, acc.x)));
        acc.y = fmaf(v.x, wa, fmaf(v.y, wb, fmaf(v.z, wc, acc.y)));
        acc.z = fmaf(v.y, wa, fmaf(v.z, wb, fmaf(v.w, wc, acc.z)));
        acc.w = fmaf(v.z, wa, fmaf(v.w, wb, fmaf(rt,  wc, acc.w)));
    };

    for (int ci = 0; ci < CPC; ++ci) {
        const float4 vm = *(const float4*)pm;
        const float4 v0 = *(const float4*)p0;
        const float4 vp = *(const float4*)pp;
        pm += HWc; p0 += HWc; pp += HWc;

        const float4 u0 = swu[ci * 3 + 0];   // wu0..3
        const float4 u1 = swu[ci * 3 + 1];   // wu4..7
        const float4 u2 = swu[ci * 3 + 2];   // wu8 in .x
        const float4 q0 = swv[ci * 3 + 0];
        const float4 q1 = swv[ci * 3 + 1];
        const float4 q2 = swv[ci * 3 + 2];

        // reflect in w handled via lane shuffles + boundary override
        float lm = __shfl_up(vm.w, 1);  float rm = __shfl_down(vm.x, 1);
        float l0 = __shfl_up(v0.w, 1);  float r0 = __shfl_down(v0.x, 1);
        float lp = __shfl_up(vp.w, 1);  float rp = __shfl_down(vp.x, 1);
        if (w4 == 0)  { lm = vm.y; l0 = v0.y; lp = vp.y; }
        if (w4 == 31) { rm = vm.z; r0 = v0.z; rp = vp.z; }

        // u output: rows hm (wu0-2), h (wu3-5), hp (wu6-8)
        row_acc(lm, vm, rm, u0.x, u0.y, u0.z, au);
        row_acc(l0, v0, r0, u0.w, u1.x, u1.y, au);
        row_acc(lp, vp, rp, u1.z, u1.w, u2.x, au);
        // v output
        row_acc(lm, vm, rm, q0.x, q0.y, q0.z, av);
        row_acc(l0, v0, r0, q0.w, q1.x, q1.y, av);
        row_acc(lp, vp, rp, q1.z, q1.w, q2.x, av);
    }

    // ---- accumulate partial (this chunk's 64 channels) into output ----
    float* ou = out + ((size_t)(b * 2 + 0) * Hc + h) * Wc + w4 * 4;
    float* ov = out + ((size_t)(b * 2 + 1) * Hc + h) * Wc + w4 * 4;
    atomicAdd(ou + 0, au.x); atomicAdd(ou + 1, au.y);
    atomicAdd(ou + 2, au.z); atomicAdd(ou + 3, au.w);
    atomicAdd(ov + 0, av.x); atomicAdd(ov + 1, av.y);
    atomicAdd(ov + 2, av.z); atomicAdd(ov + 3, av.w);
}

extern "C" void kernel_launch(void* const* d_in, const int* in_sizes, int n_in,
                              void* d_out, int out_size, void* d_ws, size_t ws_size,
                              hipStream_t stream) {
    const float* x  = (const float*)d_in[0];
    const float* ku = (const float*)d_in[1];
    const float* kv = (const float*)d_in[2];
    const int*   ui = (const int*)d_in[3];
    const int*   vi = (const int*)d_in[4];
    float* out = (float*)d_out;

    // 1,048,576 output floats = 262,144 float4
    zero_out_kernel<<<512, 512, 0, stream>>>((float4*)out);

    dim3 grid(TILES, Bc, CHUNKS);   // 8 x 32 x 4 = 1024 blocks, 512 thr each
    modbank_kernel<<<grid, 512, 0, stream>>>(x, ku, kv, ui, vi, out);
}